// Round 2
// baseline (224.977 us; speedup 1.0000x reference)
//
#include <hip/hip_runtime.h>

#define IN_CAPS 2048
#define K_DIM   16
#define OD      512      // out_caps(32) * out_dim(16)
#define NCH     64       // i-chunks for partial sums
#define ICH     32       // i's per chunk (IN_CAPS / NCH)

__device__ __forceinline__ float dot4(const float4& a, const float4& b) {
    return fmaf(a.x, b.x, fmaf(a.y, b.y, fmaf(a.z, b.z, a.w * b.w)));
}

// K1: u_hat[b,i,od] = sum_k W[i,od,k] * x[b,i,k] (fp32),
// plus s0 partials with uniform c = 1/32 (softmax of zeros).
// Block: 256 threads, handles BTILE b's x 32 i's. Thread t owns od = 2t, 2t+1.
template<int BTILE>
__global__ __launch_bounds__(256)
void k_uhat(const float* __restrict__ x,     // [..][2048][16] (b0 pre-offset)
            const float* __restrict__ W,     // [2048][512][16]
            float* __restrict__ u,           // [nb][2048][512]
            float* __restrict__ part)        // [nb][NCH][512]
{
    const int t   = threadIdx.x;
    const int ic  = blockIdx.x;            // 0..NCH-1
    const int bl0 = blockIdx.y * BTILE;    // local b base
    const int i0  = ic * ICH;

    __shared__ float xs[BTILE * ICH * K_DIM];
    {
        const int nf4 = BTILE * ICH * K_DIM / 4;   // BTILE*128
        for (int idx = t; idx < nf4; idx += 256) {
            const int bb = idx / (ICH * K_DIM / 4);
            const int f  = idx % (ICH * K_DIM / 4);
            const float4* src = (const float4*)(x + ((size_t)(bl0 + bb) * IN_CAPS + i0) * K_DIM);
            ((float4*)xs)[idx] = src[f];
        }
    }
    __syncthreads();

    float acc[2 * BTILE];
#pragma unroll
    for (int j = 0; j < 2 * BTILE; ++j) acc[j] = 0.f;

    for (int ii = 0; ii < ICH; ++ii) {
        const int i = i0 + ii;
        const float4* wp = (const float4*)(W + ((size_t)i * OD + 2 * t) * K_DIM);
        const float4 w0a = wp[0], w0b = wp[1], w0c = wp[2], w0d = wp[3];
        const float4 w1a = wp[4], w1b = wp[5], w1c = wp[6], w1d = wp[7];
#pragma unroll
        for (int bb = 0; bb < BTILE; ++bb) {
            const float4* xv = (const float4*)&xs[(bb * ICH + ii) * K_DIM];
            const float4 xa = xv[0], xb = xv[1], xc = xv[2], xd = xv[3];
            float u0 = dot4(w0a, xa) + dot4(w0b, xb) + dot4(w0c, xc) + dot4(w0d, xd);
            float u1 = dot4(w1a, xa) + dot4(w1b, xb) + dot4(w1c, xc) + dot4(w1d, xd);
            acc[2 * bb]     += u0;
            acc[2 * bb + 1] += u1;
            ((float2*)(u + ((size_t)(bl0 + bb) * IN_CAPS + i) * OD))[t] = make_float2(u0, u1);
        }
    }
#pragma unroll
    for (int bb = 0; bb < BTILE; ++bb) {
        float2 pr = make_float2(acc[2 * bb] * (1.f / 32.f), acc[2 * bb + 1] * (1.f / 32.f));
        ((float2*)(part + ((size_t)(bl0 + bb) * NCH + ic) * OD))[t] = pr;
    }
}

// K3/K5 (fused routing pass): per (b,i): a = sum_d u*v; b_ij update; c = softmax_o;
// accumulate partial s += c*u.  Wave layout: lane l -> o = l>>1, d-half = l&1 (8 d's).
template<bool FIRST>
__global__ __launch_bounds__(256)
void k_route(const float* __restrict__ u,    // [nb][2048][512]
             const float* __restrict__ v,    // [nb][512]
             float* __restrict__ bij,        // [nb][2048][32]
             float* __restrict__ part)       // [nb][NCH][512]
{
    const int t  = threadIdx.x;
    const int l  = t & 63;
    const int w  = t >> 6;
    const int ic = blockIdx.x;   // 0..NCH-1
    const int b  = blockIdx.y;   // local b
    const int o  = l >> 1;
    const int dh = l & 1;

    float vr[8];
    {
        const float* vp = v + (size_t)b * OD + o * 16 + dh * 8;
        const float4 va = *(const float4*)vp;
        const float4 vb = *(const float4*)(vp + 4);
        vr[0] = va.x; vr[1] = va.y; vr[2] = va.z; vr[3] = va.w;
        vr[4] = vb.x; vr[5] = vb.y; vr[6] = vb.z; vr[7] = vb.w;
    }
    float acc[8];
#pragma unroll
    for (int j = 0; j < 8; ++j) acc[j] = 0.f;

    const int ibase = ic * ICH + w * (ICH / 4);
    for (int ii = 0; ii < ICH / 4; ++ii) {
        const int i = ibase + ii;
        const float* up = u + ((size_t)b * IN_CAPS + i) * OD + l * 8;
        const float4 u0 = *(const float4*)up;
        const float4 u1 = *(const float4*)(up + 4);
        float uu[8] = {u0.x, u0.y, u0.z, u0.w, u1.x, u1.y, u1.z, u1.w};

        float ah = 0.f;
#pragma unroll
        for (int j = 0; j < 8; ++j) ah = fmaf(uu[j], vr[j], ah);
        float a = ah + __shfl_xor(ah, 1);

        float* bp = bij + ((size_t)b * IN_CAPS + i) * 32;
        if (FIRST) {
            if (dh == 0) bp[o] = a;
        } else {
            a += bp[o];
        }
        // softmax over o (each o duplicated on 2 lanes)
        float m = a;
#pragma unroll
        for (int s = 1; s < 64; s <<= 1) m = fmaxf(m, __shfl_xor(m, s));
        const float e = __expf(a - m);
        float ssum = e;
#pragma unroll
        for (int s = 1; s < 64; s <<= 1) ssum += __shfl_xor(ssum, s);
        const float c = e * (2.f / ssum);   // wave-sum counts each o twice
#pragma unroll
        for (int j = 0; j < 8; ++j) acc[j] = fmaf(c, uu[j], acc[j]);
    }

    __shared__ float red[4][OD];
#pragma unroll
    for (int j = 0; j < 8; ++j) red[w][l * 8 + j] = acc[j];
    __syncthreads();
    const float s0 = red[0][t] + red[1][t] + red[2][t] + red[3][t];
    const float s1 = red[0][t + 256] + red[1][t + 256] + red[2][t + 256] + red[3][t + 256];
    float* pp = part + ((size_t)b * NCH + ic) * OD;
    pp[t]       = s0;
    pp[t + 256] = s1;
}

// K2/K4/K6: reduce partials over chunks, squash, write v (or d_out).
__global__ __launch_bounds__(256)
void k_reduce(const float* __restrict__ part, float* __restrict__ vout, int nb)
{
    const int idx = blockIdx.x * 256 + threadIdx.x;
    if (idx >= nb * OD) return;
    const int b  = idx >> 9;
    const int od = idx & (OD - 1);
    const float* p = part + (size_t)b * NCH * OD + od;
    float s = 0.f;
#pragma unroll
    for (int ch = 0; ch < NCH; ++ch) s += p[(size_t)ch * OD];
    const float sq = s * s;
    vout[idx] = sq * s / ((1.f + sq) * sqrtf(sq + 1e-8f));
}

extern "C" void kernel_launch(void* const* d_in, const int* in_sizes, int n_in,
                              void* d_out, int out_size, void* d_ws, size_t ws_size,
                              hipStream_t stream)
{
    const float* x = (const float*)d_in[0];   // [64][2048][16]
    const float* W = (const float*)d_in[1];   // [2048][32][16][16]
    float* out = (float*)d_out;               // [64][32][16][1]

    const size_t U_B    = (size_t)IN_CAPS * OD * 4;   // 4 MiB / b
    const size_t BIJ_B  = (size_t)IN_CAPS * 32 * 4;   // 256 KiB / b
    const size_t PART_B = (size_t)NCH * OD * 4;       // 128 KiB / b
    const size_t V_B    = (size_t)OD * 4;             // 2 KiB / b
    const size_t PER_B  = U_B + BIJ_B + PART_B + 2 * V_B;

    int nb = 64;
    while (nb > 1 && (size_t)nb * PER_B > ws_size) nb >>= 1;

    char* wsc = (char*)d_ws;
    for (int b0 = 0; b0 < 64; b0 += nb) {
        float* u    = (float*)wsc;
        float* bij  = (float*)(wsc + (size_t)nb * U_B);
        float* part = (float*)(wsc + (size_t)nb * (U_B + BIJ_B));
        float* v0   = (float*)(wsc + (size_t)nb * (U_B + BIJ_B + PART_B));
        float* v1   = v0 + (size_t)nb * OD;

        const float* xb = x + (size_t)b0 * IN_CAPS * K_DIM;
        const int btile = (nb >= 8) ? 8 : nb;
        dim3 g1(NCH, nb / btile);
        switch (btile) {
            case 8: k_uhat<8><<<g1, 256, 0, stream>>>(xb, W, u, part); break;
            case 4: k_uhat<4><<<g1, 256, 0, stream>>>(xb, W, u, part); break;
            case 2: k_uhat<2><<<g1, 256, 0, stream>>>(xb, W, u, part); break;
            default: k_uhat<1><<<g1, 256, 0, stream>>>(xb, W, u, part); break;
        }
        const int rblocks = (nb * OD + 255) / 256;
        k_reduce<<<rblocks, 256, 0, stream>>>(part, v0, nb);
        k_route<true ><<<dim3(NCH, nb), 256, 0, stream>>>(u, v0, bij, part);
        k_reduce<<<rblocks, 256, 0, stream>>>(part, v1, nb);
        k_route<false><<<dim3(NCH, nb), 256, 0, stream>>>(u, v1, bij, part);
        k_reduce<<<rblocks, 256, 0, stream>>>(part, out + (size_t)b0 * OD, nb);
    }
}